// Round 7
// baseline (180.797 us; speedup 1.0000x reference)
//
#include <hip/hip_runtime.h>
#include <hip/hip_bf16.h>

// B=32, N=207, T=24, E=128, H=8, d=16, DM=64, M=32
#define Bn 32
#define Nn 207
#define Tt 24
#define Ee 128
#define Hh 8
#define Dm 64
#define Mm 32
#define NBN (Bn * Nn)                // 6624
#define PT ((size_t)Nn * 16384)     // per-tensor Pt fragment elems

typedef __attribute__((ext_vector_type(8))) short bf16x8;
typedef __attribute__((ext_vector_type(4))) float f32x4;

__device__ __forceinline__ unsigned swz256(unsigned a) { return a ^ (((a >> 8) & 7u) << 4); }
__device__ __forceinline__ unsigned swz64(unsigned a)  { return a ^ (((a >> 7) & 3u) << 4); }
// hardware packed f32->bf16 (RNE): 1 VALU op per pair
__device__ __forceinline__ unsigned cvtpk(float lo, float hi) {
  unsigned r;
  asm("v_cvt_pk_bf16_f32 %0, %1, %2" : "=v"(r) : "v"(lo), "v"(hi));
  return r;
}
__device__ __forceinline__ unsigned short f2bs(float f) {
  return (unsigned short)cvtpk(f, f);
}
__device__ __forceinline__ bf16x8 pack8(float4 a, float4 b) {
  union { unsigned u[4]; bf16x8 v; } w;
  w.u[0] = cvtpk(a.x, a.y);
  w.u[1] = cvtpk(a.z, a.w);
  w.u[2] = cvtpk(b.x, b.y);
  w.u[3] = cvtpk(b.z, b.w);
  return w.v;
}

// P[n][i][col] = sum_m p1[n*64+i/2][m] * p2[m][(i&1)*128+col] -> bf16 B-fragments:
// Pt[(((n*8+nt)*4+ks)*64 + lane)*8 + j] = P[n][ks*32+(lane>>4)*8+j][nt*16+(lane&15)]
__global__ __launch_bounds__(256) void build_P_frag3(
    const float* __restrict__ qp1, const float* __restrict__ qp2,
    const float* __restrict__ kp1, const float* __restrict__ kp2,
    const float* __restrict__ vp1, const float* __restrict__ vp2,
    unsigned short* __restrict__ Pt) {
  const int tau = blockIdx.y;
  const float* p1 = (tau == 0) ? qp1 : (tau == 1) ? kp1 : vp1;
  const float* p2 = (tau == 0) ? qp2 : (tau == 1) ? kp2 : vp2;
  unsigned short* dst = Pt + (size_t)tau * PT;
  const int bid = blockIdx.x;
  const int n = bid >> 3;
  const int r8 = bid & 7;
  const int ks = r8 >> 1;
  const int chunk = ((r8 & 1) << 1) + (threadIdx.x >> 7);
  const int col = threadIdx.x & 127;
  const int base_i = ks * 32 + chunk * 8;
  const float* p1r = p1 + (size_t)(n * 64 + (base_i >> 1)) * Mm;
  const float* p2a = p2 + col;
  const float* p2b = p2 + 128 + col;
  float acc[8] = {};
#pragma unroll
  for (int m = 0; m < Mm; ++m) {
    float a = p2a[m * 256], b = p2b[m * 256];
#pragma unroll
    for (int jj = 0; jj < 4; ++jj) {
      float pv = p1r[jj * Mm + m];
      acc[2 * jj]     = fmaf(pv, a, acc[2 * jj]);
      acc[2 * jj + 1] = fmaf(pv, b, acc[2 * jj + 1]);
    }
  }
  const int nt = col >> 4;
  const int lane = (chunk << 4) | (col & 15);
  union { unsigned u[4]; uint4 v; } w;
#pragma unroll
  for (int jj = 0; jj < 4; ++jj) w.u[jj] = cvtpk(acc[2 * jj], acc[2 * jj + 1]);
  *(uint4*)(dst + (size_t)(((n * 8 + nt) * 4 + ks) * 64 + lane) * 8) = w.v;
}

__global__ __launch_bounds__(256) void build_W_frag(const float* __restrict__ W,
                                                    unsigned short* __restrict__ Wt) {
  for (int idx = threadIdx.x; idx < 1024; idx += 256) {
    int lane = idx & 63, ks = (idx >> 6) & 3, nt = idx >> 8;
    union { unsigned u[4]; uint4 v; } w;
#pragma unroll
    for (int jj = 0; jj < 4; ++jj) {
      float a = W[(size_t)(ks * 32 + (lane >> 4) * 8 + 2 * jj) * 64 + nt * 16 + (lane & 15)];
      float b = W[(size_t)(ks * 32 + (lane >> 4) * 8 + 2 * jj + 1) * 64 + nt * 16 + (lane & 15)];
      w.u[jj] = cvtpk(a, b);
    }
    *(uint4*)(Wt + (size_t)idx * 8) = w.v;
  }
}

// One block per (b,n); 4 waves; 32768 B LDS -> 5 blocks/CU (20 waves/CU).
// Map: XQ=0 (6K xq stage), XK=6144 (6K xk stage),
//      QS=12288 (6K q-proj, pre-scaled 0.25), KS=18432 (6K k-proj),
//      VST=24576 (8K v-proj transposed [128][32] swz64, s>=24 zeroed in P0).
// Overlays: probs bf16[8][24][32] swz64 @0 (over XQ+XK, dead after P1);
//           outh bf16[24][128] swz256 @12288 (over QS, dead after P2 scores).
// v-proj A-frags load DIRECT from global (no XV staging), hidden under softmax.
// Chain (4 barriers): stage2 | proj q,k | scores+softmax+probs+v-proj | PV+attn | outproj
__global__ __launch_bounds__(256, 4) void fused_attn(
    const float* __restrict__ Qin, const float* __restrict__ Kin,
    const float* __restrict__ Vin,
    const unsigned short* __restrict__ Ptq, const unsigned short* __restrict__ Ptk,
    const unsigned short* __restrict__ Ptv, const unsigned short* __restrict__ Wt,
    const float* __restrict__ bias,
    float* __restrict__ out, float* __restrict__ attn) {
  __shared__ __align__(16) char smem[32768];
  const int tid = threadIdx.x;
  const int lane = tid & 63;
  const int wv = tid >> 6;
  const int c = lane & 15;
  const int g = lane >> 4;
  const f32x4 zf = {0.f, 0.f, 0.f, 0.f};
  const bf16x8 zb = {0, 0, 0, 0, 0, 0, 0, 0};

  int bx = blockIdx.x;
  bx = (bx & 7) * 828 + (bx >> 3);          // bijective XCD swizzle (6624 = 8*828)
  const int n = bx >> 5;
  const int b = bx & 31;
  const size_t xbase = (size_t)(b * Nn + n) * (Tt * Ee);

  // ---- P0: zero VST; stage xq->XQ, xk->XK (bf16, swz256) ----
  {
    uint4 z4 = {0, 0, 0, 0};
    *(uint4*)(smem + 24576 + tid * 32) = z4;
    *(uint4*)(smem + 24576 + tid * 32 + 16) = z4;
    const float* src[2] = {Qin + xbase, Kin + xbase};
#pragma unroll
    for (int w = 0; w < 2; ++w)
#pragma unroll
      for (int it = 0; it < 3; ++it) {
        int e4 = tid + 256 * it;            // 768 float4 = 24x128
        float4 xv = *(const float4*)(src[w] + (size_t)e4 * 4);
        unsigned a = swz256((unsigned)((e4 >> 5) * 256 + (e4 & 31) * 8));
        uint2 pk;
        pk.x = cvtpk(xv.x, xv.y);
        pk.y = cvtpk(xv.z, xv.w);
        *(uint2*)(smem + w * 6144 + a) = pk;
      }
  }
  __syncthreads();  // (1) stages ready

  // ---- P1: proj q->QS (x0.25), k->KS ----
  {
#pragma unroll
    for (int w = 0; w < 2; ++w) {
      const unsigned short* Pf = (w == 0) ? Ptq : Ptk;
      f32x4 acc[2][2] = {{zf, zf}, {zf, zf}};
#pragma unroll
      for (int ks = 0; ks < 4; ++ks) {
        bf16x8 Bf[2], Af[2];
#pragma unroll
        for (int ntl = 0; ntl < 2; ++ntl)
          Bf[ntl] = *(const bf16x8*)(Pf + (size_t)(((n * 8 + (wv * 2 + ntl)) * 4 + ks) * 64 + lane) * 8);
#pragma unroll
        for (int mt = 0; mt < 2; ++mt) {
          int row = mt * 16 + c; row = row < 24 ? row : 23;
          Af[mt] = *(const bf16x8*)(smem + w * 6144 + swz256((unsigned)(row * 256 + ks * 64 + g * 16)));
        }
        __builtin_amdgcn_s_setprio(1);
#pragma unroll
        for (int mt = 0; mt < 2; ++mt)
#pragma unroll
          for (int ntl = 0; ntl < 2; ++ntl)
            acc[mt][ntl] = __builtin_amdgcn_mfma_f32_16x16x32_bf16(Af[mt], Bf[ntl], acc[mt][ntl], 0, 0, 0);
        __builtin_amdgcn_s_setprio(0);
      }
      const float postscale = (w == 0) ? 0.25f : 1.0f;  // fold softmax scale into q
      char* dst = smem + 12288 + w * 6144;
#pragma unroll
      for (int mt = 0; mt < 2; ++mt)
#pragma unroll
        for (int r = 0; r < 4; ++r) {
          int row = mt * 16 + g * 4 + r;
          if (row < 24) {
#pragma unroll
            for (int ntl = 0; ntl < 2; ++ntl) {
              int col = (wv * 2 + ntl) * 16 + c;
              *(unsigned short*)(dst + swz256((unsigned)(row * 256 + col * 2))) =
                  f2bs(fmaxf(acc[mt][ntl][r], 0.f) * postscale);
            }
          }
        }
    }
  }
  __syncthreads();  // (2) QS/KS ready; XQ/XK dead

  // ---- P2: scores + softmax + probs@0; v A-frags direct-global + v-proj -> VST ----
  {
    // scores
    f32x4 sc[2][2][2];
#pragma unroll
    for (int hh = 0; hh < 2; ++hh) {
      int h = wv * 2 + hh;
      bf16x8 Aq[2], Bk[2];
#pragma unroll
      for (int mt = 0; mt < 2; ++mt) {
        int row = mt * 16 + c; row = row < 24 ? row : 23;
        Aq[mt] = zb;
        if (lane < 32) Aq[mt] = *(const bf16x8*)(smem + 12288 + swz256((unsigned)(row * 256 + (h * 16 + g * 8) * 2)));
      }
#pragma unroll
      for (int st = 0; st < 2; ++st) {
        int row = st * 16 + c; row = row < 24 ? row : 23;
        Bk[st] = zb;
        if (lane < 32) Bk[st] = *(const bf16x8*)(smem + 18432 + swz256((unsigned)(row * 256 + (h * 16 + g * 8) * 2)));
      }
      __builtin_amdgcn_s_setprio(1);
#pragma unroll
      for (int mt = 0; mt < 2; ++mt)
#pragma unroll
        for (int st = 0; st < 2; ++st)
          sc[hh][mt][st] = __builtin_amdgcn_mfma_f32_16x16x32_bf16(Aq[mt], Bk[st], zf, 0, 0, 0);
      __builtin_amdgcn_s_setprio(0);
    }

    // issue v A-frag loads for mt=0 (rows 0..15): latency hides under softmax
    const float* vbase = Vin + xbase;
    float4 vr[8];
#pragma unroll
    for (int ks = 0; ks < 4; ++ks) {
      const float* p = vbase + (size_t)c * Ee + ks * 32 + g * 8;
      vr[2 * ks]     = *(const float4*)p;
      vr[2 * ks + 1] = *(const float4*)(p + 4);
    }

    // softmax (no max pass: q,k >= 0, q pre-scaled) + probs -> LDS @0
#pragma unroll
    for (int hh = 0; hh < 2; ++hh) {
      int h = wv * 2 + hh;
#pragma unroll
      for (int mt = 0; mt < 2; ++mt)
#pragma unroll
        for (int r = 0; r < 4; ++r) {
          int t = mt * 16 + g * 4 + r;
          float e0 = (c <= t)      ? __expf(sc[hh][mt][0][r]) : 0.f;
          float e1 = (16 + c <= t) ? __expf(sc[hh][mt][1][r]) : 0.f;
          float s2 = e0 + e1;
          s2 += __shfl_xor(s2, 1);
          s2 += __shfl_xor(s2, 2);
          s2 += __shfl_xor(s2, 4);
          s2 += __shfl_xor(s2, 8);
          float inv = 1.0f / s2;
          float p0 = e0 * inv, p1 = e1 * inv;
          if (t < 24) {
            *(unsigned short*)(smem + swz64((unsigned)(h * 1536 + t * 64 + c * 2)))        = f2bs(p0);
            *(unsigned short*)(smem + swz64((unsigned)(h * 1536 + t * 64 + (16 + c) * 2))) = f2bs(p1);
          }
        }
    }

    // v-proj mt=0 (A from regs), then mt=1 batch
    f32x4 vacc[2][2] = {{zf, zf}, {zf, zf}};
    {
      bf16x8 va[4];
#pragma unroll
      for (int ks = 0; ks < 4; ++ks) va[ks] = pack8(vr[2 * ks], vr[2 * ks + 1]);
#pragma unroll
      for (int ks = 0; ks < 4; ++ks) {
#pragma unroll
        for (int ntl = 0; ntl < 2; ++ntl) {
          bf16x8 Bf = *(const bf16x8*)(Ptv + (size_t)(((n * 8 + (wv * 2 + ntl)) * 4 + ks) * 64 + lane) * 8);
          vacc[0][ntl] = __builtin_amdgcn_mfma_f32_16x16x32_bf16(va[ks], Bf, vacc[0][ntl], 0, 0, 0);
        }
      }
      int row1 = 16 + c; row1 = row1 < 24 ? row1 : 23;
#pragma unroll
      for (int ks = 0; ks < 4; ++ks) {
        const float* p = vbase + (size_t)row1 * Ee + ks * 32 + g * 8;
        vr[2 * ks]     = *(const float4*)p;
        vr[2 * ks + 1] = *(const float4*)(p + 4);
      }
#pragma unroll
      for (int ks = 0; ks < 4; ++ks) va[ks] = pack8(vr[2 * ks], vr[2 * ks + 1]);
#pragma unroll
      for (int ks = 0; ks < 4; ++ks) {
#pragma unroll
        for (int ntl = 0; ntl < 2; ++ntl) {
          bf16x8 Bf = *(const bf16x8*)(Ptv + (size_t)(((n * 8 + (wv * 2 + ntl)) * 4 + ks) * 64 + lane) * 8);
          vacc[1][ntl] = __builtin_amdgcn_mfma_f32_16x16x32_bf16(va[ks], Bf, vacc[1][ntl], 0, 0, 0);
        }
      }
    }
    // VST write (transposed [dcol][srow], relu)
#pragma unroll
    for (int mt = 0; mt < 2; ++mt)
#pragma unroll
      for (int r = 0; r < 4; ++r) {
        int srow = mt * 16 + g * 4 + r;
        if (srow < 24) {
#pragma unroll
          for (int ntl = 0; ntl < 2; ++ntl) {
            int dcol = (wv * 2 + ntl) * 16 + c;
            *(unsigned short*)(smem + 24576 + swz64((unsigned)(dcol * 64 + srow * 2))) =
                f2bs(fmaxf(vacc[mt][ntl][r], 0.f));
          }
        }
      }
  }
  __syncthreads();  // (3) probs + VST ready; QS/KS dead

  // ---- P3: PV -> outh @12288 (over QS); coalesced attn write from probs LDS ----
  {
    f32x4 pv[2][2];
#pragma unroll
    for (int hh = 0; hh < 2; ++hh) {
      int h = wv * 2 + hh;
      bf16x8 Bv = *(const bf16x8*)(smem + 24576 + swz64((unsigned)((h * 16 + c) * 64 + g * 16)));
#pragma unroll
      for (int mt = 0; mt < 2; ++mt) {
        int row = mt * 16 + c; row = row < 24 ? row : 23;
        bf16x8 Ap = *(const bf16x8*)(smem + swz64((unsigned)(h * 1536 + row * 64 + g * 16)));
        pv[hh][mt] = __builtin_amdgcn_mfma_f32_16x16x32_bf16(Ap, Bv, zf, 0, 0, 0);
      }
    }
    // attn: 1152 float4 per block, coalesced (values = bf16-rounded probs, = PV input)
    const size_t abase = (size_t)(b * Nn + n) * (Hh * Tt * Tt);
#pragma unroll
    for (int i = 0; i < 5; ++i) {
      int fidx = tid + 256 * i;
      if (fidx < 1152) {
        int h = fidx / 144;
        int rem = fidx - h * 144;
        int t = rem / 6;
        int s4 = (rem - t * 6) * 4;
        uint2 pr = *(const uint2*)(smem + swz64((unsigned)(h * 1536 + t * 64 + s4 * 2)));
        float4 o;
        o.x = __uint_as_float((pr.x & 0xFFFFu) << 16);
        o.y = __uint_as_float(pr.x & 0xFFFF0000u);
        o.z = __uint_as_float((pr.y & 0xFFFFu) << 16);
        o.w = __uint_as_float(pr.y & 0xFFFF0000u);
        *(float4*)(attn + abase + (size_t)h * 576 + t * 24 + s4) = o;
      }
    }
#pragma unroll
    for (int hh = 0; hh < 2; ++hh) {
      int h = wv * 2 + hh;
#pragma unroll
      for (int mt = 0; mt < 2; ++mt)
#pragma unroll
        for (int r = 0; r < 4; ++r) {
          int t = mt * 16 + g * 4 + r;
          if (t < 24)
            *(unsigned short*)(smem + 12288 + swz256((unsigned)(t * 256 + (h * 16 + c) * 2))) =
                f2bs(pv[hh][mt][r]);
        }
    }
  }
  __syncthreads();  // (4) outh ready

  // ---- P4: out projection (wave wv owns cols wv*16+c) + bias, relu ----
  {
    f32x4 acc2[2] = {zf, zf};
#pragma unroll
    for (int ks = 0; ks < 4; ++ks) {
      bf16x8 Bw = *(const bf16x8*)(Wt + (size_t)((wv * 4 + ks) * 64 + lane) * 8);
      bf16x8 Af[2];
#pragma unroll
      for (int mt = 0; mt < 2; ++mt) {
        int row = mt * 16 + c; row = row < 24 ? row : 23;
        Af[mt] = *(const bf16x8*)(smem + 12288 + swz256((unsigned)(row * 256 + ks * 64 + g * 16)));
      }
      __builtin_amdgcn_s_setprio(1);
#pragma unroll
      for (int mt = 0; mt < 2; ++mt)
        acc2[mt] = __builtin_amdgcn_mfma_f32_16x16x32_bf16(Af[mt], Bw, acc2[mt], 0, 0, 0);
      __builtin_amdgcn_s_setprio(0);
    }
    int j = wv * 16 + c;
    float bj = bias[j];
    const size_t obase = (size_t)(b * Nn + n) * (Tt * Dm);
#pragma unroll
    for (int mt = 0; mt < 2; ++mt)
#pragma unroll
      for (int r = 0; r < 4; ++r) {
        int t = mt * 16 + g * 4 + r;
        if (t < 24) out[obase + (size_t)t * Dm + j] = fmaxf(acc2[mt][r] + bj, 0.f);
      }
  }
}

extern "C" void kernel_launch(void* const* d_in, const int* in_sizes, int n_in,
                              void* d_out, int out_size, void* d_ws, size_t ws_size,
                              hipStream_t stream) {
  const float* query = (const float*)d_in[0];
  const float* key   = (const float*)d_in[1];
  const float* value = (const float*)d_in[2];
  const float* qp1 = (const float*)d_in[4];
  const float* qp2 = (const float*)d_in[5];
  const float* kp1 = (const float*)d_in[6];
  const float* kp2 = (const float*)d_in[7];
  const float* vp1 = (const float*)d_in[8];
  const float* vp2 = (const float*)d_in[9];
  const float* out_W = (const float*)d_in[10];
  const float* out_b = (const float*)d_in[11];

  unsigned short* Pt  = (unsigned short*)d_ws;        // 3*PT bf16
  unsigned short* Wtf = Pt + 3 * PT;                  // 8192 bf16

  float* out = (float*)d_out;
  float* attn = out + (size_t)NBN * Tt * Dm;

  build_P_frag3<<<dim3(Nn * 8, 3), 256, 0, stream>>>(qp1, qp2, kp1, kp2, vp1, vp2, Pt);
  build_W_frag<<<1, 256, 0, stream>>>(out_W, Wtf);
  fused_attn<<<NBN, 256, 0, stream>>>(query, key, value,
                                      Pt, Pt + PT, Pt + 2 * PT, Wtf,
                                      out_b, out, attn);
}

// Round 8
// 163.561 us; speedup vs baseline: 1.1054x; 1.1054x over previous
//
#include <hip/hip_runtime.h>
#include <hip/hip_bf16.h>

// B=32, N=207, T=24, E=128, H=8, d=16, DM=64, M=32
#define Bn 32
#define Nn 207
#define Tt 24
#define Ee 128
#define Hh 8
#define Dm 64
#define Mm 32
#define NBN (Bn * Nn)                // 6624
#define PT ((size_t)Nn * 16384)     // per-tensor Pt fragment elems

typedef __attribute__((ext_vector_type(8))) short bf16x8;
typedef __attribute__((ext_vector_type(4))) float f32x4;

__device__ __forceinline__ unsigned swz256(unsigned a) { return a ^ (((a >> 8) & 7u) << 4); }
__device__ __forceinline__ unsigned swz64(unsigned a)  { return a ^ (((a >> 7) & 3u) << 4); }
// hardware packed f32->bf16 (RNE)
__device__ __forceinline__ unsigned cvtpk(float lo, float hi) {
  unsigned r;
  asm("v_cvt_pk_bf16_f32 %0, %1, %2" : "=v"(r) : "v"(lo), "v"(hi));
  return r;
}
__device__ __forceinline__ unsigned short f2bs(float f) {
  return (unsigned short)cvtpk(f, f);
}

// ---------------- builders (unchanged from R6) ----------------
__global__ __launch_bounds__(256) void build_P_frag3(
    const float* __restrict__ qp1, const float* __restrict__ qp2,
    const float* __restrict__ kp1, const float* __restrict__ kp2,
    const float* __restrict__ vp1, const float* __restrict__ vp2,
    unsigned short* __restrict__ Pt) {
  const int tau = blockIdx.y;
  const float* p1 = (tau == 0) ? qp1 : (tau == 1) ? kp1 : vp1;
  const float* p2 = (tau == 0) ? qp2 : (tau == 1) ? kp2 : vp2;
  unsigned short* dst = Pt + (size_t)tau * PT;
  const int bid = blockIdx.x;
  const int n = bid >> 3;
  const int r8 = bid & 7;
  const int ks = r8 >> 1;
  const int chunk = ((r8 & 1) << 1) + (threadIdx.x >> 7);
  const int col = threadIdx.x & 127;
  const int base_i = ks * 32 + chunk * 8;
  const float* p1r = p1 + (size_t)(n * 64 + (base_i >> 1)) * Mm;
  const float* p2a = p2 + col;
  const float* p2b = p2 + 128 + col;
  float acc[8] = {};
#pragma unroll
  for (int m = 0; m < Mm; ++m) {
    float a = p2a[m * 256], b = p2b[m * 256];
#pragma unroll
    for (int jj = 0; jj < 4; ++jj) {
      float pv = p1r[jj * Mm + m];
      acc[2 * jj]     = fmaf(pv, a, acc[2 * jj]);
      acc[2 * jj + 1] = fmaf(pv, b, acc[2 * jj + 1]);
    }
  }
  const int nt = col >> 4;
  const int lane = (chunk << 4) | (col & 15);
  union { unsigned u[4]; uint4 v; } w;
#pragma unroll
  for (int jj = 0; jj < 4; ++jj) w.u[jj] = cvtpk(acc[2 * jj], acc[2 * jj + 1]);
  *(uint4*)(dst + (size_t)(((n * 8 + nt) * 4 + ks) * 64 + lane) * 8) = w.v;
}

__global__ __launch_bounds__(256) void build_W_frag(const float* __restrict__ W,
                                                    unsigned short* __restrict__ Wt) {
  for (int idx = threadIdx.x; idx < 1024; idx += 256) {
    int lane = idx & 63, ks = (idx >> 6) & 3, nt = idx >> 8;
    union { unsigned u[4]; uint4 v; } w;
#pragma unroll
    for (int jj = 0; jj < 4; ++jj) {
      float a = W[(size_t)(ks * 32 + (lane >> 4) * 8 + 2 * jj) * 64 + nt * 16 + (lane & 15)];
      float b = W[(size_t)(ks * 32 + (lane >> 4) * 8 + 2 * jj + 1) * 64 + nt * 16 + (lane & 15)];
      w.u[jj] = cvtpk(a, b);
    }
    *(uint4*)(Wt + (size_t)idx * 8) = w.v;
  }
}

// One block per (b,n); 4 waves; 38912 B LDS -> 4 blocks/CU.
// WAVE-AUTONOMOUS: wave wv owns cols 32wv..32wv+31 == heads {2wv,2wv+1} through
// proj -> scores -> softmax -> probs -> PV. Only 2 barriers:
//   (1) after staging (all waves read all staged rows)
//   (2) before outproj (reads all e-columns of outh)
// LDS: XQ@0, XK@6144, XV@12288 (staging, swz256)
//      QB@18432 (12KB): QS rows [t][col2^((t&3)<<4)] / KS @+6144; per-wave 64B
//        col-slices later overlaid by probs[h][t][s] and then outh[eblk=h][t][e_in]
//        at slot(h) = (h&1)*6144 + (h>>1)*64  (same-wave WAR, LDS in-order)
//      VST@30720 (8KB): v-proj^T [128][32] swz64, s>=24 zeroed per-wave.
__global__ __launch_bounds__(256, 4) void fused_attn(
    const float* __restrict__ Qin, const float* __restrict__ Kin,
    const float* __restrict__ Vin,
    const unsigned short* __restrict__ Ptq, const unsigned short* __restrict__ Ptk,
    const unsigned short* __restrict__ Ptv, const unsigned short* __restrict__ Wt,
    const float* __restrict__ bias,
    float* __restrict__ out, float* __restrict__ attn) {
  __shared__ __align__(16) char smem[38912];
  const int tid = threadIdx.x;
  const int lane = tid & 63;
  const int wv = tid >> 6;
  const int c = lane & 15;
  const int g = lane >> 4;
  const f32x4 zf = {0.f, 0.f, 0.f, 0.f};
  const bf16x8 zb = {0, 0, 0, 0, 0, 0, 0, 0};

  int bx = blockIdx.x;
  bx = (bx & 7) * 828 + (bx >> 3);          // bijective XCD swizzle (6624 = 8*828)
  const int n = bx >> 5;
  const int b = bx & 31;
  const size_t xbase = (size_t)(b * Nn + n) * (Tt * Ee);

  // ---- P0: stage xq/xk/xv (swz256); zero own VST cols s=24..31 ----
  {
    if (g < 2) {   // 32 lanes: dcol = 32*wv + (lane&31)
      unsigned dcol = (unsigned)(32 * wv + (lane & 31));
      uint4 z4 = {0, 0, 0, 0};
      *(uint4*)(smem + 30720 + swz64(dcol * 64 + 48)) = z4;
    }
    const float* src[3] = {Qin + xbase, Kin + xbase, Vin + xbase};
#pragma unroll
    for (int w = 0; w < 3; ++w)
#pragma unroll
      for (int it = 0; it < 3; ++it) {
        int e4 = tid + 256 * it;            // 768 float4 = 24x128
        float4 xv = *(const float4*)(src[w] + (size_t)e4 * 4);
        unsigned a = swz256((unsigned)((e4 >> 5) * 256 + (e4 & 31) * 8));
        uint2 pk;
        pk.x = cvtpk(xv.x, xv.y);
        pk.y = cvtpk(xv.z, xv.w);
        *(uint2*)(smem + w * 6144 + a) = pk;
      }
  }
  __syncthreads();  // (1) staging ready -- the ONLY cross-wave input

  // =================== wave-autonomous section ===================
  // ---- q-proj -> QS own cols (x0.25), k-proj -> KS own cols ----
#pragma unroll
  for (int w = 0; w < 2; ++w) {
    const unsigned short* Pf = (w == 0) ? Ptq : Ptk;
    f32x4 acc[2][2] = {{zf, zf}, {zf, zf}};
#pragma unroll
    for (int ks = 0; ks < 4; ++ks) {
      bf16x8 Bf[2], Af[2];
#pragma unroll
      for (int ntl = 0; ntl < 2; ++ntl)
        Bf[ntl] = *(const bf16x8*)(Pf + (size_t)(((n * 8 + (wv * 2 + ntl)) * 4 + ks) * 64 + lane) * 8);
#pragma unroll
      for (int mt = 0; mt < 2; ++mt) {
        int row = mt * 16 + c; row = row < 24 ? row : 23;
        Af[mt] = *(const bf16x8*)(smem + w * 6144 + swz256((unsigned)(row * 256 + ks * 64 + g * 16)));
      }
      __builtin_amdgcn_s_setprio(1);
#pragma unroll
      for (int mt = 0; mt < 2; ++mt)
#pragma unroll
        for (int ntl = 0; ntl < 2; ++ntl)
          acc[mt][ntl] = __builtin_amdgcn_mfma_f32_16x16x32_bf16(Af[mt], Bf[ntl], acc[mt][ntl], 0, 0, 0);
      __builtin_amdgcn_s_setprio(0);
    }
    const float postscale = (w == 0) ? 0.25f : 1.0f;
#pragma unroll
    for (int mt = 0; mt < 2; ++mt)
#pragma unroll
      for (int r = 0; r < 4; ++r) {
        int row = mt * 16 + g * 4 + r;
        if (row < 24) {
#pragma unroll
          for (int ntl = 0; ntl < 2; ++ntl) {
            unsigned col2 = (unsigned)((2 * wv + ntl) * 32 + c * 2);
            unsigned ad = 18432u + w * 6144u + row * 256u + (col2 ^ (((unsigned)row & 3u) << 4));
            *(unsigned short*)(smem + ad) = f2bs(fmaxf(acc[mt][ntl][r], 0.f) * postscale);
          }
        }
      }
  }

  // ---- v-proj -> VST own cols (transposed, relu) ----
  {
    f32x4 acc[2][2] = {{zf, zf}, {zf, zf}};
#pragma unroll
    for (int ks = 0; ks < 4; ++ks) {
      bf16x8 Bf[2], Af[2];
#pragma unroll
      for (int ntl = 0; ntl < 2; ++ntl)
        Bf[ntl] = *(const bf16x8*)(Ptv + (size_t)(((n * 8 + (wv * 2 + ntl)) * 4 + ks) * 64 + lane) * 8);
#pragma unroll
      for (int mt = 0; mt < 2; ++mt) {
        int row = mt * 16 + c; row = row < 24 ? row : 23;
        Af[mt] = *(const bf16x8*)(smem + 12288 + swz256((unsigned)(row * 256 + ks * 64 + g * 16)));
      }
      __builtin_amdgcn_s_setprio(1);
#pragma unroll
      for (int mt = 0; mt < 2; ++mt)
#pragma unroll
        for (int ntl = 0; ntl < 2; ++ntl)
          acc[mt][ntl] = __builtin_amdgcn_mfma_f32_16x16x32_bf16(Af[mt], Bf[ntl], acc[mt][ntl], 0, 0, 0);
      __builtin_amdgcn_s_setprio(0);
    }
#pragma unroll
    for (int mt = 0; mt < 2; ++mt)
#pragma unroll
      for (int r = 0; r < 4; ++r) {
        int srow = mt * 16 + g * 4 + r;
        if (srow < 24) {
#pragma unroll
          for (int ntl = 0; ntl < 2; ++ntl) {
            int dcol = (wv * 2 + ntl) * 16 + c;
            *(unsigned short*)(smem + 30720 + swz64((unsigned)(dcol * 64 + srow * 2))) =
                f2bs(fmaxf(acc[mt][ntl][r], 0.f));
          }
        }
      }
  }

  // ---- scores (own heads, own QS/KS cols) ----
  f32x4 sc[2][2][2];
#pragma unroll
  for (int hh = 0; hh < 2; ++hh) {
    int h = wv * 2 + hh;
    bf16x8 Aq[2], Bk[2];
#pragma unroll
    for (int mt = 0; mt < 2; ++mt) {
      int row = mt * 16 + c; row = row < 24 ? row : 23;
      Aq[mt] = zb;
      if (lane < 32) {
        unsigned col2 = (unsigned)(h * 32 + g * 16);
        Aq[mt] = *(const bf16x8*)(smem + 18432u + row * 256u + (col2 ^ (((unsigned)row & 3u) << 4)));
      }
    }
#pragma unroll
    for (int st = 0; st < 2; ++st) {
      int row = st * 16 + c; row = row < 24 ? row : 23;
      Bk[st] = zb;
      if (lane < 32) {
        unsigned col2 = (unsigned)(h * 32 + g * 16);
        Bk[st] = *(const bf16x8*)(smem + 24576u + row * 256u + (col2 ^ (((unsigned)row & 3u) << 4)));
      }
    }
    __builtin_amdgcn_s_setprio(1);
#pragma unroll
    for (int mt = 0; mt < 2; ++mt)
#pragma unroll
      for (int st = 0; st < 2; ++st)
        sc[hh][mt][st] = __builtin_amdgcn_mfma_f32_16x16x32_bf16(Aq[mt], Bk[st], zf, 0, 0, 0);
    __builtin_amdgcn_s_setprio(0);
  }

  // ---- softmax + probs (overlay own QS/KS slices; after own scores reads) ----
  // slot(h) = 18432 + (h&1)*6144 + (h>>1)*64 ; elem (t, s): + t*256 + (s*2 ^ ((t&3)<<4))
#pragma unroll
  for (int hh = 0; hh < 2; ++hh) {
    int h = wv * 2 + hh;
    unsigned slot = 18432u + ((unsigned)h & 1u) * 6144u + ((unsigned)h >> 1) * 64u;
#pragma unroll
    for (int mt = 0; mt < 2; ++mt)
#pragma unroll
      for (int r = 0; r < 4; ++r) {
        int t = mt * 16 + g * 4 + r;
        float e0 = (c <= t)      ? __expf(sc[hh][mt][0][r]) : 0.f;
        float e1 = (16 + c <= t) ? __expf(sc[hh][mt][1][r]) : 0.f;
        float s2 = e0 + e1;
        s2 += __shfl_xor(s2, 1);
        s2 += __shfl_xor(s2, 2);
        s2 += __shfl_xor(s2, 4);
        s2 += __shfl_xor(s2, 8);
        float inv = 1.0f / s2;
        float p0 = e0 * inv, p1 = e1 * inv;
        if (t < 24) {
          unsigned sw = ((unsigned)t & 3u) << 4;
          *(unsigned short*)(smem + slot + t * 256u + (((unsigned)(c * 2)) ^ sw))      = f2bs(p0);
          *(unsigned short*)(smem + slot + t * 256u + (((unsigned)(32 + c * 2)) ^ sw)) = f2bs(p1);
        }
      }
  }

  // ---- PV (reads own probs + own VST), attn write, outh overlay write ----
  {
    bf16x8 Ap[2][2], Bv[2];
#pragma unroll
    for (int hh = 0; hh < 2; ++hh) {
      int h = wv * 2 + hh;
      unsigned slot = 18432u + ((unsigned)h & 1u) * 6144u + ((unsigned)h >> 1) * 64u;
      Bv[hh] = *(const bf16x8*)(smem + 30720 + swz64((unsigned)((h * 16 + c) * 64 + g * 16)));
#pragma unroll
      for (int mt = 0; mt < 2; ++mt) {
        int row = mt * 16 + c; row = row < 24 ? row : 23;
        Ap[hh][mt] = *(const bf16x8*)(smem + slot + row * 256u +
                                      (((unsigned)(g * 16)) ^ (((unsigned)row & 3u) << 4)));
      }
    }
    // attn global write (own heads) -- reads probs BEFORE outh overwrites them
    const size_t abase = (size_t)(b * Nn + n) * (Hh * Tt * Tt);
#pragma unroll
    for (int i = 0; i < 5; ++i) {
      int idx = lane + 64 * i;
      if (idx < 288) {
        int h_rel = idx / 144;
        int rem = idx - h_rel * 144;
        int t = rem / 6;
        int s4g = rem - t * 6;
        int h = wv * 2 + h_rel;
        unsigned slot = 18432u + ((unsigned)h & 1u) * 6144u + ((unsigned)h >> 1) * 64u;
        uint2 pr = *(const uint2*)(smem + slot + t * 256u +
                                   (((unsigned)(s4g * 8)) ^ (((unsigned)t & 3u) << 4)));
        float4 o;
        o.x = __uint_as_float((pr.x & 0xFFFFu) << 16);
        o.y = __uint_as_float(pr.x & 0xFFFF0000u);
        o.z = __uint_as_float((pr.y & 0xFFFFu) << 16);
        o.w = __uint_as_float(pr.y & 0xFFFF0000u);
        *(float4*)(attn + abase + (size_t)h * 576 + t * 24 + s4g * 4) = o;
      }
    }
    f32x4 pv[2][2];
    __builtin_amdgcn_s_setprio(1);
#pragma unroll
    for (int hh = 0; hh < 2; ++hh)
#pragma unroll
      for (int mt = 0; mt < 2; ++mt)
        pv[hh][mt] = __builtin_amdgcn_mfma_f32_16x16x32_bf16(Ap[hh][mt], Bv[hh], zf, 0, 0, 0);
    __builtin_amdgcn_s_setprio(0);
    // outh[t][e=h*16+c] -> slot(h) overlay (same bytes as own probs; WAR within wave)
#pragma unroll
    for (int hh = 0; hh < 2; ++hh) {
      int h = wv * 2 + hh;
      unsigned slot = 18432u + ((unsigned)h & 1u) * 6144u + ((unsigned)h >> 1) * 64u;
#pragma unroll
      for (int mt = 0; mt < 2; ++mt)
#pragma unroll
        for (int r = 0; r < 4; ++r) {
          int t = mt * 16 + g * 4 + r;
          if (t < 24) {
            unsigned ad = slot + t * 256u + (((unsigned)(c * 2)) ^ (((unsigned)t & 3u) << 4));
            *(unsigned short*)(smem + ad) = f2bs(pv[hh][mt][r]);
          }
        }
    }
  }
  __syncthreads();  // (2) outh complete (all e-columns)

  // ---- outproj: out[t][j] = relu(sum_e outh[t][e] W[e][j] + b) ----
  {
    f32x4 acc2[2] = {zf, zf};
#pragma unroll
    for (int ks = 0; ks < 4; ++ks) {
      bf16x8 Bw = *(const bf16x8*)(Wt + (size_t)((wv * 4 + ks) * 64 + lane) * 8);
      bf16x8 Af[2];
#pragma unroll
      for (int mt = 0; mt < 2; ++mt) {
        int row = mt * 16 + c; row = row < 24 ? row : 23;
        // eblk = 2*ks + (g>>1); e_in2 = (g&1)*16
        unsigned ad = 18432u + ((unsigned)(g >> 1)) * 6144u + ((unsigned)ks) * 64u + row * 256u +
                      ((((unsigned)(g & 1)) * 16u) ^ (((unsigned)row & 3u) << 4));
        Af[mt] = *(const bf16x8*)(smem + ad);
      }
      __builtin_amdgcn_s_setprio(1);
#pragma unroll
      for (int mt = 0; mt < 2; ++mt)
        acc2[mt] = __builtin_amdgcn_mfma_f32_16x16x32_bf16(Af[mt], Bw, acc2[mt], 0, 0, 0);
      __builtin_amdgcn_s_setprio(0);
    }
    int j = wv * 16 + c;
    float bj = bias[j];
    const size_t obase = (size_t)(b * Nn + n) * (Tt * Dm);
#pragma unroll
    for (int mt = 0; mt < 2; ++mt)
#pragma unroll
      for (int r = 0; r < 4; ++r) {
        int t = mt * 16 + g * 4 + r;
        if (t < 24) out[obase + (size_t)t * Dm + j] = fmaxf(acc2[mt][r] + bj, 0.f);
      }
  }
}

extern "C" void kernel_launch(void* const* d_in, const int* in_sizes, int n_in,
                              void* d_out, int out_size, void* d_ws, size_t ws_size,
                              hipStream_t stream) {
  const float* query = (const float*)d_in[0];
  const float* key   = (const float*)d_in[1];
  const float* value = (const float*)d_in[2];
  const float* qp1 = (const float*)d_in[4];
  const float* qp2 = (const float*)d_in[5];
  const float* kp1 = (const float*)d_in[6];
  const float* kp2 = (const float*)d_in[7];
  const float* vp1 = (const float*)d_in[8];
  const float* vp2 = (const float*)d_in[9];
  const float* out_W = (const float*)d_in[10];
  const float* out_b = (const float*)d_in[11];

  unsigned short* Pt  = (unsigned short*)d_ws;        // 3*PT bf16
  unsigned short* Wtf = Pt + 3 * PT;                  // 8192 bf16

  float* out = (float*)d_out;
  float* attn = out + (size_t)NBN * Tt * Dm;

  build_P_frag3<<<dim3(Nn * 8, 3), 256, 0, stream>>>(qp1, qp2, kp1, kp2, vp1, vp2, Pt);
  build_W_frag<<<1, 256, 0, stream>>>(out_W, Wtf);
  fused_attn<<<NBN, 256, 0, stream>>>(query, key, value,
                                      Pt, Pt + PT, Pt + 2 * PT, Wtf,
                                      out_b, out, attn);
}

// Round 9
// 161.041 us; speedup vs baseline: 1.1227x; 1.0156x over previous
//
#include <hip/hip_runtime.h>
#include <hip/hip_bf16.h>

// B=32, N=207, T=24, E=128, H=8, d=16, DM=64, M=32
#define Bn 32
#define Nn 207
#define Tt 24
#define Ee 128
#define Hh 8
#define Dm 64
#define Mm 32
#define NBN (Bn * Nn)                // 6624
#define PT ((size_t)Nn * 16384)     // per-tensor Pt fragment elems

typedef __attribute__((ext_vector_type(8))) short bf16x8;
typedef __attribute__((ext_vector_type(4))) float f32x4;

__device__ __forceinline__ unsigned swz256(unsigned a) { return a ^ (((a >> 8) & 7u) << 4); }
// hardware packed f32->bf16 (RNE)
__device__ __forceinline__ unsigned cvtpk(float lo, float hi) {
  unsigned r;
  asm("v_cvt_pk_bf16_f32 %0, %1, %2" : "=v"(r) : "v"(lo), "v"(hi));
  return r;
}
__device__ __forceinline__ unsigned short f2bs(float f) {
  return (unsigned short)cvtpk(f, f);
}

// ---------------- builders (unchanged) ----------------
__global__ __launch_bounds__(256) void build_P_frag3(
    const float* __restrict__ qp1, const float* __restrict__ qp2,
    const float* __restrict__ kp1, const float* __restrict__ kp2,
    const float* __restrict__ vp1, const float* __restrict__ vp2,
    unsigned short* __restrict__ Pt) {
  const int tau = blockIdx.y;
  const float* p1 = (tau == 0) ? qp1 : (tau == 1) ? kp1 : vp1;
  const float* p2 = (tau == 0) ? qp2 : (tau == 1) ? kp2 : vp2;
  unsigned short* dst = Pt + (size_t)tau * PT;
  const int bid = blockIdx.x;
  const int n = bid >> 3;
  const int r8 = bid & 7;
  const int ks = r8 >> 1;
  const int chunk = ((r8 & 1) << 1) + (threadIdx.x >> 7);
  const int col = threadIdx.x & 127;
  const int base_i = ks * 32 + chunk * 8;
  const float* p1r = p1 + (size_t)(n * 64 + (base_i >> 1)) * Mm;
  const float* p2a = p2 + col;
  const float* p2b = p2 + 128 + col;
  float acc[8] = {};
#pragma unroll
  for (int m = 0; m < Mm; ++m) {
    float a = p2a[m * 256], b = p2b[m * 256];
#pragma unroll
    for (int jj = 0; jj < 4; ++jj) {
      float pv = p1r[jj * Mm + m];
      acc[2 * jj]     = fmaf(pv, a, acc[2 * jj]);
      acc[2 * jj + 1] = fmaf(pv, b, acc[2 * jj + 1]);
    }
  }
  const int nt = col >> 4;
  const int lane = (chunk << 4) | (col & 15);
  union { unsigned u[4]; uint4 v; } w;
#pragma unroll
  for (int jj = 0; jj < 4; ++jj) w.u[jj] = cvtpk(acc[2 * jj], acc[2 * jj + 1]);
  *(uint4*)(dst + (size_t)(((n * 8 + nt) * 4 + ks) * 64 + lane) * 8) = w.v;
}

__global__ __launch_bounds__(256) void build_W_frag(const float* __restrict__ W,
                                                    unsigned short* __restrict__ Wt) {
  for (int idx = threadIdx.x; idx < 1024; idx += 256) {
    int lane = idx & 63, ks = (idx >> 6) & 3, nt = idx >> 8;
    union { unsigned u[4]; uint4 v; } w;
#pragma unroll
    for (int jj = 0; jj < 4; ++jj) {
      float a = W[(size_t)(ks * 32 + (lane >> 4) * 8 + 2 * jj) * 64 + nt * 16 + (lane & 15)];
      float b = W[(size_t)(ks * 32 + (lane >> 4) * 8 + 2 * jj + 1) * 64 + nt * 16 + (lane & 15)];
      w.u[jj] = cvtpk(a, b);
    }
    *(uint4*)(Wt + (size_t)idx * 8) = w.v;
  }
}

struct P8 { unsigned u[8]; };

// One block per (b,n); 4 waves; 24576 B LDS -> target 6 blocks/CU (24 waves).
// Phases (3 barriers):
//   stage xq/xk/xv -> bar1
//   q/k/v-proj: staging reads, acc kept in regs packed bf16 (24 regs) -> bar2
//   (staging dead) per-wave 4608B ARENA over staging: write qs/ks/vT slices,
//     read score frags, scores+softmax (hh0 probs packed in regs), probs->arena,
//     PV, attn write, outh -> bar3
//   outproj (Bw prefetched before bar3)
// Arena(wv) = smem + wv*4608: qs@0 [24][32 lcol] xor((row&3)<<4)  (1536)
//   ks@1536 same (1536) | vT@3072 [32 lcol][24 s] stride 48 (1536)
//   probs@0 [2 hh][24 t][24 s] stride 48 (2304, overlays qs/ks after all reads)
// outh @18432: [24][128] bf16 swz256 (6144).
__global__ __launch_bounds__(256, 6) void fused_attn(
    const float* __restrict__ Qin, const float* __restrict__ Kin,
    const float* __restrict__ Vin,
    const unsigned short* __restrict__ Ptq, const unsigned short* __restrict__ Ptk,
    const unsigned short* __restrict__ Ptv, const unsigned short* __restrict__ Wt,
    const float* __restrict__ bias,
    float* __restrict__ out, float* __restrict__ attn) {
  __shared__ __align__(16) char smem[24576];
  const int tid = threadIdx.x;
  const int lane = tid & 63;
  const int wv = tid >> 6;
  const int c = lane & 15;
  const int g = lane >> 4;
  const f32x4 zf = {0.f, 0.f, 0.f, 0.f};
  const bf16x8 zb = {0, 0, 0, 0, 0, 0, 0, 0};

  int bx = blockIdx.x;
  bx = (bx & 7) * 828 + (bx >> 3);          // bijective XCD swizzle (6624 = 8*828)
  const int n = bx >> 5;
  const int b = bx & 31;
  const size_t xbase = (size_t)(b * Nn + n) * (Tt * Ee);

  // ---- P0: stage xq/xk/xv (bf16, swz256) ----
  {
    const float* src[3] = {Qin + xbase, Kin + xbase, Vin + xbase};
#pragma unroll
    for (int w = 0; w < 3; ++w)
#pragma unroll
      for (int it = 0; it < 3; ++it) {
        int e4 = tid + 256 * it;            // 768 float4 = 24x128
        float4 xv = *(const float4*)(src[w] + (size_t)e4 * 4);
        unsigned a = swz256((unsigned)((e4 >> 5) * 256 + (e4 & 31) * 8));
        uint2 pk;
        pk.x = cvtpk(xv.x, xv.y);
        pk.y = cvtpk(xv.z, xv.w);
        *(uint2*)(smem + w * 6144 + a) = pk;
      }
  }
  __syncthreads();  // (1) staging ready

  // ---- P1: q/k/v proj; results packed bf16 in regs (8 uints each) ----
  P8 pq, pk_, pv_;
  {
#pragma unroll
    for (int w = 0; w < 3; ++w) {
      const unsigned short* Pf = (w == 0) ? Ptq : (w == 1) ? Ptk : Ptv;
      const char* xs = smem + w * 6144;
      f32x4 acc[2][2] = {{zf, zf}, {zf, zf}};
#pragma unroll
      for (int ks = 0; ks < 4; ++ks) {
        bf16x8 Bf[2], Af[2];
#pragma unroll
        for (int ntl = 0; ntl < 2; ++ntl)
          Bf[ntl] = *(const bf16x8*)(Pf + (size_t)(((n * 8 + (wv * 2 + ntl)) * 4 + ks) * 64 + lane) * 8);
#pragma unroll
        for (int mt = 0; mt < 2; ++mt) {
          int row = mt * 16 + c; row = row < 24 ? row : 23;
          Af[mt] = *(const bf16x8*)(xs + swz256((unsigned)(row * 256 + ks * 64 + g * 16)));
        }
        __builtin_amdgcn_s_setprio(1);
#pragma unroll
        for (int mt = 0; mt < 2; ++mt)
#pragma unroll
          for (int ntl = 0; ntl < 2; ++ntl)
            acc[mt][ntl] = __builtin_amdgcn_mfma_f32_16x16x32_bf16(Af[mt], Bf[ntl], acc[mt][ntl], 0, 0, 0);
        __builtin_amdgcn_s_setprio(0);
      }
      const float ps = (w == 0) ? 0.25f : 1.0f;   // fold softmax scale into q
      P8 r;
#pragma unroll
      for (int mt = 0; mt < 2; ++mt)
#pragma unroll
        for (int ntl = 0; ntl < 2; ++ntl)
#pragma unroll
          for (int half = 0; half < 2; ++half) {
            float a = fmaxf(acc[mt][ntl][half * 2], 0.f) * ps;
            float bb = fmaxf(acc[mt][ntl][half * 2 + 1], 0.f) * ps;
            r.u[(mt * 2 + ntl) * 2 + half] = cvtpk(a, bb);
          }
      if (w == 0) pq = r; else if (w == 1) pk_ = r; else pv_ = r;
    }
  }
  __syncthreads();  // (2) all staging reads done -> arenas live

  char* arena = smem + wv * 4608;

  // ---- P2a: unpack packed projections into arena slices ----
#pragma unroll
  for (int mt = 0; mt < 2; ++mt)
#pragma unroll
    for (int ntl = 0; ntl < 2; ++ntl)
#pragma unroll
      for (int half = 0; half < 2; ++half) {
        unsigned uq = pq.u[(mt * 2 + ntl) * 2 + half];
        unsigned uk = pk_.u[(mt * 2 + ntl) * 2 + half];
        unsigned uv = pv_.u[(mt * 2 + ntl) * 2 + half];
#pragma unroll
        for (int rr = 0; rr < 2; ++rr) {
          int row = mt * 16 + g * 4 + half * 2 + rr;
          if (row < 24) {
            unsigned short vq = (unsigned short)(rr ? (uq >> 16) : uq);
            unsigned short vk = (unsigned short)(rr ? (uk >> 16) : uk);
            unsigned short vvv = (unsigned short)(rr ? (uv >> 16) : uv);
            unsigned adqk = (unsigned)(row * 64) +
                            (((unsigned)(ntl * 32 + c * 2)) ^ (((unsigned)row & 3u) << 4));
            *(unsigned short*)(arena + adqk) = vq;
            *(unsigned short*)(arena + 1536 + adqk) = vk;
            *(unsigned short*)(arena + 3072 + (ntl * 16 + c) * 48 + row * 2) = vvv;
          }
        }
      }

  // ---- P2b: score fragments (all reads BEFORE probs overlay writes) ----
  bf16x8 Aq[2][2], Bk[2][2];   // [hh][mt/st]; hd k-dim = 16, g>=2 zero
#pragma unroll
  for (int hh = 0; hh < 2; ++hh)
#pragma unroll
    for (int mt = 0; mt < 2; ++mt) {
      int row = mt * 16 + c; row = row < 24 ? row : 23;
      unsigned ad = (unsigned)(row * 64) +
                    (((unsigned)(hh * 32 + g * 16)) ^ (((unsigned)row & 3u) << 4));
      Aq[hh][mt] = zb;
      Bk[hh][mt] = zb;
      if (g < 2) {
        Aq[hh][mt] = *(const bf16x8*)(arena + ad);
        Bk[hh][mt] = *(const bf16x8*)(arena + 1536 + ad);
      }
    }

  // ---- P2c: scores + softmax; hh0 probs packed in regs, hh1 direct ----
  unsigned pk0[8];
#pragma unroll
  for (int hh = 0; hh < 2; ++hh) {
    f32x4 sc[2][2];
    __builtin_amdgcn_s_setprio(1);
#pragma unroll
    for (int mt = 0; mt < 2; ++mt)
#pragma unroll
      for (int st = 0; st < 2; ++st)
        sc[mt][st] = __builtin_amdgcn_mfma_f32_16x16x32_bf16(Aq[hh][mt], Bk[hh][st], zf, 0, 0, 0);
    __builtin_amdgcn_s_setprio(0);
#pragma unroll
    for (int mt = 0; mt < 2; ++mt)
#pragma unroll
      for (int r = 0; r < 4; ++r) {
        int t = mt * 16 + g * 4 + r;
        float e0 = (c <= t)      ? __expf(sc[mt][0][r]) : 0.f;
        float e1 = (16 + c <= t) ? __expf(sc[mt][1][r]) : 0.f;
        float s2 = e0 + e1;
        s2 += __shfl_xor(s2, 1);
        s2 += __shfl_xor(s2, 2);
        s2 += __shfl_xor(s2, 4);
        s2 += __shfl_xor(s2, 8);
        float inv = 1.0f / s2;
        float p0 = e0 * inv, p1 = e1 * inv;
        if (hh == 0) {
          pk0[mt * 4 + r] = cvtpk(p0, p1);   // defer write until all ks reads done
        } else {
          if (t < 24) {
            *(unsigned short*)(arena + 1152 + t * 48 + c * 2) = f2bs(p0);
            if (c < 8) *(unsigned short*)(arena + 1152 + t * 48 + (16 + c) * 2) = f2bs(p1);
          }
        }
      }
  }
  // write deferred hh0 probs
#pragma unroll
  for (int mt = 0; mt < 2; ++mt)
#pragma unroll
    for (int r = 0; r < 4; ++r) {
      int t = mt * 16 + g * 4 + r;
      if (t < 24) {
        unsigned u = pk0[mt * 4 + r];
        *(unsigned short*)(arena + t * 48 + c * 2) = (unsigned short)u;
        if (c < 8) *(unsigned short*)(arena + t * 48 + (16 + c) * 2) = (unsigned short)(u >> 16);
      }
    }

  // ---- P2d: PV + attn write + outh ----
  {
    bf16x8 Ap[2][2], Bv[2];
#pragma unroll
    for (int hh = 0; hh < 2; ++hh) {
      Bv[hh] = zb;
      if (g < 3) Bv[hh] = *(const bf16x8*)(arena + 3072 + (hh * 16 + c) * 48 + g * 16);
#pragma unroll
      for (int mt = 0; mt < 2; ++mt) {
        int row = mt * 16 + c; row = row < 24 ? row : 23;
        Ap[hh][mt] = zb;
        if (g < 3) Ap[hh][mt] = *(const bf16x8*)(arena + hh * 1152 + row * 48 + g * 16);
      }
    }
    // attn global write (own heads, coalesced-ish float4)
    const size_t abase = (size_t)(b * Nn + n) * (Hh * Tt * Tt);
#pragma unroll
    for (int i = 0; i < 5; ++i) {
      int idx = lane + 64 * i;
      if (idx < 288) {
        int hh = idx / 144;
        int rem = idx - hh * 144;
        int t = rem / 6;
        int s4g = rem - t * 6;
        uint2 pr = *(const uint2*)(arena + hh * 1152 + t * 48 + s4g * 8);
        float4 o;
        o.x = __uint_as_float((pr.x & 0xFFFFu) << 16);
        o.y = __uint_as_float(pr.x & 0xFFFF0000u);
        o.z = __uint_as_float((pr.y & 0xFFFFu) << 16);
        o.w = __uint_as_float(pr.y & 0xFFFF0000u);
        *(float4*)(attn + abase + (size_t)(wv * 2 + hh) * 576 + t * 24 + s4g * 4) = o;
      }
    }
    f32x4 pv[2][2];
    __builtin_amdgcn_s_setprio(1);
#pragma unroll
    for (int hh = 0; hh < 2; ++hh)
#pragma unroll
      for (int mt = 0; mt < 2; ++mt)
        pv[hh][mt] = __builtin_amdgcn_mfma_f32_16x16x32_bf16(Ap[hh][mt], Bv[hh], zf, 0, 0, 0);
    __builtin_amdgcn_s_setprio(0);
#pragma unroll
    for (int hh = 0; hh < 2; ++hh) {
      int h = wv * 2 + hh;
#pragma unroll
      for (int mt = 0; mt < 2; ++mt)
#pragma unroll
        for (int r = 0; r < 4; ++r) {
          int t = mt * 16 + g * 4 + r;
          if (t < 24)
            *(unsigned short*)(smem + 18432 + swz256((unsigned)(t * 256 + (h * 16 + c) * 2))) =
                f2bs(pv[hh][mt][r]);
        }
    }
  }

  // prefetch W B-frags (hide L2 latency under barrier)
  bf16x8 Bw[4];
#pragma unroll
  for (int ks = 0; ks < 4; ++ks)
    Bw[ks] = *(const bf16x8*)(Wt + (size_t)((wv * 4 + ks) * 64 + lane) * 8);
  __syncthreads();  // (3) outh complete

  // ---- P3: out projection ----
  {
    f32x4 acc2[2] = {zf, zf};
#pragma unroll
    for (int ks = 0; ks < 4; ++ks) {
      bf16x8 Af[2];
#pragma unroll
      for (int mt = 0; mt < 2; ++mt) {
        int row = mt * 16 + c; row = row < 24 ? row : 23;
        Af[mt] = *(const bf16x8*)(smem + 18432 + swz256((unsigned)(row * 256 + ks * 64 + g * 16)));
      }
      __builtin_amdgcn_s_setprio(1);
#pragma unroll
      for (int mt = 0; mt < 2; ++mt)
        acc2[mt] = __builtin_amdgcn_mfma_f32_16x16x32_bf16(Af[mt], Bw[ks], acc2[mt], 0, 0, 0);
      __builtin_amdgcn_s_setprio(0);
    }
    int j = wv * 16 + c;
    float bj = bias[j];
    const size_t obase = (size_t)(b * Nn + n) * (Tt * Dm);
#pragma unroll
    for (int mt = 0; mt < 2; ++mt)
#pragma unroll
      for (int r = 0; r < 4; ++r) {
        int t = mt * 16 + g * 4 + r;
        if (t < 24) out[obase + (size_t)t * Dm + j] = fmaxf(acc2[mt][r] + bj, 0.f);
      }
  }
}

extern "C" void kernel_launch(void* const* d_in, const int* in_sizes, int n_in,
                              void* d_out, int out_size, void* d_ws, size_t ws_size,
                              hipStream_t stream) {
  const float* query = (const float*)d_in[0];
  const float* key   = (const float*)d_in[1];
  const float* value = (const float*)d_in[2];
  const float* qp1 = (const float*)d_in[4];
  const float* qp2 = (const float*)d_in[5];
  const float* kp1 = (const float*)d_in[6];
  const float* kp2 = (const float*)d_in[7];
  const float* vp1 = (const float*)d_in[8];
  const float* vp2 = (const float*)d_in[9];
  const float* out_W = (const float*)d_in[10];
  const float* out_b = (const float*)d_in[11];

  unsigned short* Pt  = (unsigned short*)d_ws;        // 3*PT bf16
  unsigned short* Wtf = Pt + 3 * PT;                  // 8192 bf16

  float* out = (float*)d_out;
  float* attn = out + (size_t)NBN * Tt * Dm;

  build_P_frag3<<<dim3(Nn * 8, 3), 256, 0, stream>>>(qp1, qp2, kp1, kp2, vp1, vp2, Pt);
  build_W_frag<<<1, 256, 0, stream>>>(out_W, Wtf);
  fused_attn<<<NBN, 256, 0, stream>>>(query, key, value,
                                      Pt, Pt + PT, Pt + 2 * PT, Wtf,
                                      out_b, out, attn);
}

// Round 10
// 149.567 us; speedup vs baseline: 1.2088x; 1.0767x over previous
//
#include <hip/hip_runtime.h>
#include <hip/hip_bf16.h>

// B=32, N=207, T=24, E=128, H=8, d=16, DM=64, M=32
#define Bn 32
#define Nn 207
#define Tt 24
#define Ee 128
#define Hh 8
#define Dm 64
#define Mm 32
#define NBN (Bn * Nn)                // 6624
#define PT ((size_t)Nn * 16384)     // per-tensor Pt fragment elems

typedef __attribute__((ext_vector_type(8))) short bf16x8;
typedef __attribute__((ext_vector_type(4))) float f32x4;

__device__ __forceinline__ unsigned swz256(unsigned a) { return a ^ (((a >> 8) & 7u) << 4); }
// hardware packed f32->bf16 (RNE)
__device__ __forceinline__ unsigned cvtpk(float lo, float hi) {
  unsigned r;
  asm("v_cvt_pk_bf16_f32 %0, %1, %2" : "=v"(r) : "v"(lo), "v"(hi));
  return r;
}
__device__ __forceinline__ unsigned short f2bs(float f) {
  return (unsigned short)cvtpk(f, f);
}

// ---------------- builders (unchanged) ----------------
__global__ __launch_bounds__(256) void build_P_frag3(
    const float* __restrict__ qp1, const float* __restrict__ qp2,
    const float* __restrict__ kp1, const float* __restrict__ kp2,
    const float* __restrict__ vp1, const float* __restrict__ vp2,
    unsigned short* __restrict__ Pt) {
  const int tau = blockIdx.y;
  const float* p1 = (tau == 0) ? qp1 : (tau == 1) ? kp1 : vp1;
  const float* p2 = (tau == 0) ? qp2 : (tau == 1) ? kp2 : vp2;
  unsigned short* dst = Pt + (size_t)tau * PT;
  const int bid = blockIdx.x;
  const int n = bid >> 3;
  const int r8 = bid & 7;
  const int ks = r8 >> 1;
  const int chunk = ((r8 & 1) << 1) + (threadIdx.x >> 7);
  const int col = threadIdx.x & 127;
  const int base_i = ks * 32 + chunk * 8;
  const float* p1r = p1 + (size_t)(n * 64 + (base_i >> 1)) * Mm;
  const float* p2a = p2 + col;
  const float* p2b = p2 + 128 + col;
  float acc[8] = {};
#pragma unroll
  for (int m = 0; m < Mm; ++m) {
    float a = p2a[m * 256], b = p2b[m * 256];
#pragma unroll
    for (int jj = 0; jj < 4; ++jj) {
      float pv = p1r[jj * Mm + m];
      acc[2 * jj]     = fmaf(pv, a, acc[2 * jj]);
      acc[2 * jj + 1] = fmaf(pv, b, acc[2 * jj + 1]);
    }
  }
  const int nt = col >> 4;
  const int lane = (chunk << 4) | (col & 15);
  union { unsigned u[4]; uint4 v; } w;
#pragma unroll
  for (int jj = 0; jj < 4; ++jj) w.u[jj] = cvtpk(acc[2 * jj], acc[2 * jj + 1]);
  *(uint4*)(dst + (size_t)(((n * 8 + nt) * 4 + ks) * 64 + lane) * 8) = w.v;
}

__global__ __launch_bounds__(256) void build_W_frag(const float* __restrict__ W,
                                                    unsigned short* __restrict__ Wt) {
  for (int idx = threadIdx.x; idx < 1024; idx += 256) {
    int lane = idx & 63, ks = (idx >> 6) & 3, nt = idx >> 8;
    union { unsigned u[4]; uint4 v; } w;
#pragma unroll
    for (int jj = 0; jj < 4; ++jj) {
      float a = W[(size_t)(ks * 32 + (lane >> 4) * 8 + 2 * jj) * 64 + nt * 16 + (lane & 15)];
      float b = W[(size_t)(ks * 32 + (lane >> 4) * 8 + 2 * jj + 1) * 64 + nt * 16 + (lane & 15)];
      w.u[jj] = cvtpk(a, b);
    }
    *(uint4*)(Wt + (size_t)idx * 8) = w.v;
  }
}

struct P8 { unsigned u[8]; };

// One block per (b,n); 4 waves; 24576 B LDS -> 6 blocks/CU (24 waves, measured R9).
// Softmax normalization via MFMA row-sum (B=ones) -> no cross-lane shuffles at all:
// probs stored UNNORMALIZED (exp, bounded e^9); PV and attn scaled by inv = rcp(sum).
// Arena(wv) = smem + wv*4608:
//   qs@0 [24][32] xor-swz (1536) | ks@1536 (1536) | inv@2304 [2][24] f32 (192)
//   vT@3072 [32][24] stride 48 (1536)
//   probs overlay @0 [2 hh][24 t][24 s] stride 48 (2304, after all qs/ks reads)
// outh @18432 [24][128] bf16 swz256.
__global__ __launch_bounds__(256, 6) void fused_attn(
    const float* __restrict__ Qin, const float* __restrict__ Kin,
    const float* __restrict__ Vin,
    const unsigned short* __restrict__ Ptq, const unsigned short* __restrict__ Ptk,
    const unsigned short* __restrict__ Ptv, const unsigned short* __restrict__ Wt,
    const float* __restrict__ bias,
    float* __restrict__ out, float* __restrict__ attn) {
  __shared__ __align__(16) char smem[24576];
  const int tid = threadIdx.x;
  const int lane = tid & 63;
  const int wv = tid >> 6;
  const int c = lane & 15;
  const int g = lane >> 4;
  const f32x4 zf = {0.f, 0.f, 0.f, 0.f};
  const bf16x8 zb = {0, 0, 0, 0, 0, 0, 0, 0};

  int bx = blockIdx.x;
  bx = (bx & 7) * 828 + (bx >> 3);          // bijective XCD swizzle (6624 = 8*828)
  const int n = bx >> 5;
  const int b = bx & 31;
  const size_t xbase = (size_t)(b * Nn + n) * (Tt * Ee);

  // ---- P0: stage xq/xk/xv (bf16, swz256) ----
  {
    const float* src[3] = {Qin + xbase, Kin + xbase, Vin + xbase};
#pragma unroll
    for (int w = 0; w < 3; ++w)
#pragma unroll
      for (int it = 0; it < 3; ++it) {
        int e4 = tid + 256 * it;            // 768 float4 = 24x128
        float4 xv = *(const float4*)(src[w] + (size_t)e4 * 4);
        unsigned a = swz256((unsigned)((e4 >> 5) * 256 + (e4 & 31) * 8));
        uint2 pk;
        pk.x = cvtpk(xv.x, xv.y);
        pk.y = cvtpk(xv.z, xv.w);
        *(uint2*)(smem + w * 6144 + a) = pk;
      }
  }
  __syncthreads();  // (1) staging ready

  // ---- P1: q/k/v proj; results packed bf16 in regs (8 uints each) ----
  P8 pq, pk_, pv_;
  {
#pragma unroll
    for (int w = 0; w < 3; ++w) {
      const unsigned short* Pf = (w == 0) ? Ptq : (w == 1) ? Ptk : Ptv;
      const char* xs = smem + w * 6144;
      f32x4 acc[2][2] = {{zf, zf}, {zf, zf}};
#pragma unroll
      for (int ks = 0; ks < 4; ++ks) {
        bf16x8 Bf[2], Af[2];
#pragma unroll
        for (int ntl = 0; ntl < 2; ++ntl)
          Bf[ntl] = *(const bf16x8*)(Pf + (size_t)(((n * 8 + (wv * 2 + ntl)) * 4 + ks) * 64 + lane) * 8);
#pragma unroll
        for (int mt = 0; mt < 2; ++mt) {
          int row = mt * 16 + c; row = row < 24 ? row : 23;
          Af[mt] = *(const bf16x8*)(xs + swz256((unsigned)(row * 256 + ks * 64 + g * 16)));
        }
        __builtin_amdgcn_s_setprio(1);
#pragma unroll
        for (int mt = 0; mt < 2; ++mt)
#pragma unroll
          for (int ntl = 0; ntl < 2; ++ntl)
            acc[mt][ntl] = __builtin_amdgcn_mfma_f32_16x16x32_bf16(Af[mt], Bf[ntl], acc[mt][ntl], 0, 0, 0);
        __builtin_amdgcn_s_setprio(0);
      }
      const float ps = (w == 0) ? 0.25f : 1.0f;   // fold softmax scale into q
      P8 r;
#pragma unroll
      for (int mt = 0; mt < 2; ++mt)
#pragma unroll
        for (int ntl = 0; ntl < 2; ++ntl)
#pragma unroll
          for (int half = 0; half < 2; ++half) {
            float a = fmaxf(acc[mt][ntl][half * 2], 0.f) * ps;
            float bb = fmaxf(acc[mt][ntl][half * 2 + 1], 0.f) * ps;
            r.u[(mt * 2 + ntl) * 2 + half] = cvtpk(a, bb);
          }
      if (w == 0) pq = r; else if (w == 1) pk_ = r; else pv_ = r;
    }
  }
  __syncthreads();  // (2) all staging reads done -> arenas live

  char* arena = smem + wv * 4608;

  // ---- P2a: unpack packed projections into arena slices ----
#pragma unroll
  for (int mt = 0; mt < 2; ++mt)
#pragma unroll
    for (int ntl = 0; ntl < 2; ++ntl)
#pragma unroll
      for (int half = 0; half < 2; ++half) {
        unsigned uq = pq.u[(mt * 2 + ntl) * 2 + half];
        unsigned uk = pk_.u[(mt * 2 + ntl) * 2 + half];
        unsigned uv = pv_.u[(mt * 2 + ntl) * 2 + half];
        int row0 = mt * 16 + g * 4 + half * 2;
        // vT: rows adjacent in [e][t] layout -> single uint store (both rows)
        if (row0 < 24)
          *(unsigned*)(arena + 3072 + (ntl * 16 + c) * 48 + row0 * 2) = uv;
#pragma unroll
        for (int rr = 0; rr < 2; ++rr) {
          int row = row0 + rr;
          if (row < 24) {
            unsigned short vq = (unsigned short)(rr ? (uq >> 16) : uq);
            unsigned short vk = (unsigned short)(rr ? (uk >> 16) : uk);
            unsigned adqk = (unsigned)(row * 64) +
                            (((unsigned)(ntl * 32 + c * 2)) ^ (((unsigned)row & 3u) << 4));
            *(unsigned short*)(arena + adqk) = vq;
            *(unsigned short*)(arena + 1536 + adqk) = vk;
          }
        }
      }

  // ---- P2b: score fragments (all reads BEFORE probs overlay writes) ----
  bf16x8 Aq[2][2], Bk[2][2];   // [hh][mt/st]; k-dim = 16, g>=2 zero
#pragma unroll
  for (int hh = 0; hh < 2; ++hh)
#pragma unroll
    for (int mt = 0; mt < 2; ++mt) {
      int row = mt * 16 + c; row = row < 24 ? row : 23;
      unsigned ad = (unsigned)(row * 64) +
                    (((unsigned)(hh * 32 + g * 16)) ^ (((unsigned)row & 3u) << 4));
      Aq[hh][mt] = zb;
      Bk[hh][mt] = zb;
      if (g < 2) {
        Aq[hh][mt] = *(const bf16x8*)(arena + ad);
        Bk[hh][mt] = *(const bf16x8*)(arena + 1536 + ad);
      }
    }

  // ---- P2c: scores + exp; store UNNORMALIZED probs (no shuffles, no reduce) ----
#pragma unroll
  for (int hh = 0; hh < 2; ++hh) {
    f32x4 sc[2][2];
    __builtin_amdgcn_s_setprio(1);
#pragma unroll
    for (int mt = 0; mt < 2; ++mt)
#pragma unroll
      for (int st = 0; st < 2; ++st)
        sc[mt][st] = __builtin_amdgcn_mfma_f32_16x16x32_bf16(Aq[hh][mt], Bk[hh][st], zf, 0, 0, 0);
    __builtin_amdgcn_s_setprio(0);
#pragma unroll
    for (int mt = 0; mt < 2; ++mt)
#pragma unroll
      for (int r = 0; r < 4; ++r) {
        int t = mt * 16 + g * 4 + r;
        float e0 = (c <= t)      ? __expf(sc[mt][0][r]) : 0.f;   // bounded by e^9
        float e1 = (16 + c <= t) ? __expf(sc[mt][1][r]) : 0.f;
        if (t < 24) {
          unsigned u = cvtpk(e0, e1);
          *(unsigned short*)(arena + hh * 1152 + t * 48 + c * 2) = (unsigned short)u;
          if (c < 8)
            *(unsigned short*)(arena + hh * 1152 + t * 48 + (16 + c) * 2) = (unsigned short)(u >> 16);
        }
      }
  }

  // ---- P2d: row-sum MFMA (B=ones) + PV; normalize in regs; attn; outh ----
  {
    bf16x8 Ap[2][2], Bv[2];
    const short one_bf = (short)0x3F80;
    bf16x8 onesf = {one_bf, one_bf, one_bf, one_bf, one_bf, one_bf, one_bf, one_bf};
    if (g >= 3) onesf = zb;   // k = g*8+j < 24 only
#pragma unroll
    for (int hh = 0; hh < 2; ++hh) {
      Bv[hh] = zb;
      if (g < 3) Bv[hh] = *(const bf16x8*)(arena + 3072 + (hh * 16 + c) * 48 + g * 16);
#pragma unroll
      for (int mt = 0; mt < 2; ++mt) {
        int row = mt * 16 + c; row = row < 24 ? row : 23;
        Ap[hh][mt] = zb;
        if (g < 3) Ap[hh][mt] = *(const bf16x8*)(arena + hh * 1152 + row * 48 + g * 16);
      }
    }
    f32x4 pv[2][2], su[2][2];
    __builtin_amdgcn_s_setprio(1);
#pragma unroll
    for (int hh = 0; hh < 2; ++hh)
#pragma unroll
      for (int mt = 0; mt < 2; ++mt) {
        su[hh][mt] = __builtin_amdgcn_mfma_f32_16x16x32_bf16(Ap[hh][mt], onesf, zf, 0, 0, 0);
        pv[hh][mt] = __builtin_amdgcn_mfma_f32_16x16x32_bf16(Ap[hh][mt], Bv[hh], zf, 0, 0, 0);
      }
    __builtin_amdgcn_s_setprio(0);
    // normalize pv rows; store inv (rows t = mt*16+g*4+r) for the attn write
#pragma unroll
    for (int hh = 0; hh < 2; ++hh)
#pragma unroll
      for (int mt = 0; mt < 2; ++mt) {
        float iv[4];
#pragma unroll
        for (int r = 0; r < 4; ++r) {
          iv[r] = __builtin_amdgcn_rcpf(su[hh][mt][r]);   // sum >= 1 for valid t
          pv[hh][mt][r] *= iv[r];
        }
        if (c == 0) {
#pragma unroll
          for (int rp = 0; rp < 4; rp += 2) {
            int t0 = mt * 16 + g * 4 + rp;
            if (t0 < 24) {
              float2 st2 = {iv[rp], iv[rp + 1]};
              *(float2*)(arena + 2304 + hh * 96 + t0 * 4) = st2;
            }
          }
        }
      }
    // attn global write: p_un * inv[t] (coalesced float4)
    const size_t abase = (size_t)(b * Nn + n) * (Hh * Tt * Tt);
#pragma unroll
    for (int i = 0; i < 5; ++i) {
      int idx = lane + 64 * i;
      if (idx < 288) {
        int hh = idx / 144;
        int rem = idx - hh * 144;
        int t = rem / 6;
        int s4g = rem - t * 6;
        uint2 pr = *(const uint2*)(arena + hh * 1152 + t * 48 + s4g * 8);
        float iv0 = *(const float*)(arena + 2304 + hh * 96 + t * 4);
        float4 o;
        o.x = __uint_as_float((pr.x & 0xFFFFu) << 16) * iv0;
        o.y = __uint_as_float(pr.x & 0xFFFF0000u) * iv0;
        o.z = __uint_as_float((pr.y & 0xFFFFu) << 16) * iv0;
        o.w = __uint_as_float(pr.y & 0xFFFF0000u) * iv0;
        *(float4*)(attn + abase + (size_t)(wv * 2 + hh) * 576 + t * 24 + s4g * 4) = o;
      }
    }
    // outh
#pragma unroll
    for (int hh = 0; hh < 2; ++hh) {
      int h = wv * 2 + hh;
#pragma unroll
      for (int mt = 0; mt < 2; ++mt)
#pragma unroll
        for (int r = 0; r < 4; ++r) {
          int t = mt * 16 + g * 4 + r;
          if (t < 24)
            *(unsigned short*)(smem + 18432 + swz256((unsigned)(t * 256 + (h * 16 + c) * 2))) =
                f2bs(pv[hh][mt][r]);
        }
    }
  }

  // prefetch W B-frags (hide L2 latency under barrier)
  bf16x8 Bw[4];
#pragma unroll
  for (int ks = 0; ks < 4; ++ks)
    Bw[ks] = *(const bf16x8*)(Wt + (size_t)((wv * 4 + ks) * 64 + lane) * 8);
  __syncthreads();  // (3) outh complete

  // ---- P3: out projection ----
  {
    f32x4 acc2[2] = {zf, zf};
#pragma unroll
    for (int ks = 0; ks < 4; ++ks) {
      bf16x8 Af[2];
#pragma unroll
      for (int mt = 0; mt < 2; ++mt) {
        int row = mt * 16 + c; row = row < 24 ? row : 23;
        Af[mt] = *(const bf16x8*)(smem + 18432 + swz256((unsigned)(row * 256 + ks * 64 + g * 16)));
      }
      __builtin_amdgcn_s_setprio(1);
#pragma unroll
      for (int mt = 0; mt < 2; ++mt)
        acc2[mt] = __builtin_amdgcn_mfma_f32_16x16x32_bf16(Af[mt], Bw[ks], acc2[mt], 0, 0, 0);
      __builtin_amdgcn_s_setprio(0);
    }
    int j = wv * 16 + c;
    float bj = bias[j];
    const size_t obase = (size_t)(b * Nn + n) * (Tt * Dm);
#pragma unroll
    for (int mt = 0; mt < 2; ++mt)
#pragma unroll
      for (int r = 0; r < 4; ++r) {
        int t = mt * 16 + g * 4 + r;
        if (t < 24) out[obase + (size_t)t * Dm + j] = fmaxf(acc2[mt][r] + bj, 0.f);
      }
  }
}

extern "C" void kernel_launch(void* const* d_in, const int* in_sizes, int n_in,
                              void* d_out, int out_size, void* d_ws, size_t ws_size,
                              hipStream_t stream) {
  const float* query = (const float*)d_in[0];
  const float* key   = (const float*)d_in[1];
  const float* value = (const float*)d_in[2];
  const float* qp1 = (const float*)d_in[4];
  const float* qp2 = (const float*)d_in[5];
  const float* kp1 = (const float*)d_in[6];
  const float* kp2 = (const float*)d_in[7];
  const float* vp1 = (const float*)d_in[8];
  const float* vp2 = (const float*)d_in[9];
  const float* out_W = (const float*)d_in[10];
  const float* out_b = (const float*)d_in[11];

  unsigned short* Pt  = (unsigned short*)d_ws;        // 3*PT bf16
  unsigned short* Wtf = Pt + 3 * PT;                  // 8192 bf16

  float* out = (float*)d_out;
  float* attn = out + (size_t)NBN * Tt * Dm;

  build_P_frag3<<<dim3(Nn * 8, 3), 256, 0, stream>>>(qp1, qp2, kp1, kp2, vp1, vp2, Pt);
  build_W_frag<<<1, 256, 0, stream>>>(out_W, Wtf);
  fused_attn<<<NBN, 256, 0, stream>>>(query, key, value,
                                      Pt, Pt + PT, Pt + 2 * PT, Wtf,
                                      out_b, out, attn);
}

// Round 13
// 148.561 us; speedup vs baseline: 1.2170x; 1.0068x over previous
//
#include <hip/hip_runtime.h>
#include <hip/hip_bf16.h>

// B=32, N=207, T=24, E=128, H=8, d=16, DM=64, M=32
#define Bn 32
#define Nn 207
#define Tt 24
#define Ee 128
#define Hh 8
#define Dm 64
#define Mm 32
#define NBN (Bn * Nn)                // 6624
#define PT ((size_t)Nn * 16384)     // per-tensor Pt fragment elems

typedef __attribute__((ext_vector_type(8))) short bf16x8;
typedef __attribute__((ext_vector_type(4))) float f32x4;

__device__ __forceinline__ unsigned swz256(unsigned a) { return a ^ (((a >> 8) & 7u) << 4); }
// hardware packed f32->bf16 (RNE)
__device__ __forceinline__ unsigned cvtpk(float lo, float hi) {
  unsigned r;
  asm("v_cvt_pk_bf16_f32 %0, %1, %2" : "=v"(r) : "v"(lo), "v"(hi));
  return r;
}
__device__ __forceinline__ unsigned short f2bs(float f) {
  return (unsigned short)cvtpk(f, f);
}

// ---------------- builders (unchanged) ----------------
__global__ __launch_bounds__(256) void build_P_frag3(
    const float* __restrict__ qp1, const float* __restrict__ qp2,
    const float* __restrict__ kp1, const float* __restrict__ kp2,
    const float* __restrict__ vp1, const float* __restrict__ vp2,
    unsigned short* __restrict__ Pt) {
  const int tau = blockIdx.y;
  const float* p1 = (tau == 0) ? qp1 : (tau == 1) ? kp1 : vp1;
  const float* p2 = (tau == 0) ? qp2 : (tau == 1) ? kp2 : vp2;
  unsigned short* dst = Pt + (size_t)tau * PT;
  const int bid = blockIdx.x;
  const int n = bid >> 3;
  const int r8 = bid & 7;
  const int ks = r8 >> 1;
  const int chunk = ((r8 & 1) << 1) + (threadIdx.x >> 7);
  const int col = threadIdx.x & 127;
  const int base_i = ks * 32 + chunk * 8;
  const float* p1r = p1 + (size_t)(n * 64 + (base_i >> 1)) * Mm;
  const float* p2a = p2 + col;
  const float* p2b = p2 + 128 + col;
  float acc[8] = {};
#pragma unroll
  for (int m = 0; m < Mm; ++m) {
    float a = p2a[m * 256], b = p2b[m * 256];
#pragma unroll
    for (int jj = 0; jj < 4; ++jj) {
      float pv = p1r[jj * Mm + m];
      acc[2 * jj]     = fmaf(pv, a, acc[2 * jj]);
      acc[2 * jj + 1] = fmaf(pv, b, acc[2 * jj + 1]);
    }
  }
  const int nt = col >> 4;
  const int lane = (chunk << 4) | (col & 15);
  union { unsigned u[4]; uint4 v; } w;
#pragma unroll
  for (int jj = 0; jj < 4; ++jj) w.u[jj] = cvtpk(acc[2 * jj], acc[2 * jj + 1]);
  *(uint4*)(dst + (size_t)(((n * 8 + nt) * 4 + ks) * 64 + lane) * 8) = w.v;
}

__global__ __launch_bounds__(256) void build_W_frag(const float* __restrict__ W,
                                                    unsigned short* __restrict__ Wt) {
  for (int idx = threadIdx.x; idx < 1024; idx += 256) {
    int lane = idx & 63, ks = (idx >> 6) & 3, nt = idx >> 8;
    union { unsigned u[4]; uint4 v; } w;
#pragma unroll
    for (int jj = 0; jj < 4; ++jj) {
      float a = W[(size_t)(ks * 32 + (lane >> 4) * 8 + 2 * jj) * 64 + nt * 16 + (lane & 15)];
      float b = W[(size_t)(ks * 32 + (lane >> 4) * 8 + 2 * jj + 1) * 64 + nt * 16 + (lane & 15)];
      w.u[jj] = cvtpk(a, b);
    }
    *(uint4*)(Wt + (size_t)idx * 8) = w.v;
  }
}

struct P8 { unsigned u[8]; };

// One block per (b,n); 4 waves; 24576 B LDS -> 6 blocks/CU (24 waves, measured R9).
// Softmax normalization via MFMA row-sum (B=ones) -> no cross-lane shuffles at all:
// probs stored UNNORMALIZED (exp, bounded e^9); PV and attn scaled by inv = rcp(sum).
// Arena(wv) = smem + wv*4608:
//   qs@0 [24][32] xor-swz (1536) | ks@1536 (1536) | inv@2304 [2][24] f32 (192)
//   vT@3072 [32][24] stride 48 (1536)
//   probs overlay @0 [2 hh][24 t][24 s] stride 48 (2304, after all qs/ks reads)
// outh @18432 [24][128] bf16 swz256.
// NOTE (R11/R12 lesson): both the 8-block arena-overlay variant AND a
// semantically-equivalent P0/P1 reschedule of THIS kernel failed correctness
// (out absmax ~5e-2, schedule-sensitive). This exact source passed at 149.6us
// with 5x error margin. Do not perturb without a fence-instrumented experiment.
__global__ __launch_bounds__(256, 6) void fused_attn(
    const float* __restrict__ Qin, const float* __restrict__ Kin,
    const float* __restrict__ Vin,
    const unsigned short* __restrict__ Ptq, const unsigned short* __restrict__ Ptk,
    const unsigned short* __restrict__ Ptv, const unsigned short* __restrict__ Wt,
    const float* __restrict__ bias,
    float* __restrict__ out, float* __restrict__ attn) {
  __shared__ __align__(16) char smem[24576];
  const int tid = threadIdx.x;
  const int lane = tid & 63;
  const int wv = tid >> 6;
  const int c = lane & 15;
  const int g = lane >> 4;
  const f32x4 zf = {0.f, 0.f, 0.f, 0.f};
  const bf16x8 zb = {0, 0, 0, 0, 0, 0, 0, 0};

  int bx = blockIdx.x;
  bx = (bx & 7) * 828 + (bx >> 3);          // bijective XCD swizzle (6624 = 8*828)
  const int n = bx >> 5;
  const int b = bx & 31;
  const size_t xbase = (size_t)(b * Nn + n) * (Tt * Ee);

  // ---- P0: stage xq/xk/xv (bf16, swz256) ----
  {
    const float* src[3] = {Qin + xbase, Kin + xbase, Vin + xbase};
#pragma unroll
    for (int w = 0; w < 3; ++w)
#pragma unroll
      for (int it = 0; it < 3; ++it) {
        int e4 = tid + 256 * it;            // 768 float4 = 24x128
        float4 xv = *(const float4*)(src[w] + (size_t)e4 * 4);
        unsigned a = swz256((unsigned)((e4 >> 5) * 256 + (e4 & 31) * 8));
        uint2 pk;
        pk.x = cvtpk(xv.x, xv.y);
        pk.y = cvtpk(xv.z, xv.w);
        *(uint2*)(smem + w * 6144 + a) = pk;
      }
  }
  __syncthreads();  // (1) staging ready

  // ---- P1: q/k/v proj; results packed bf16 in regs (8 uints each) ----
  P8 pq, pk_, pv_;
  {
#pragma unroll
    for (int w = 0; w < 3; ++w) {
      const unsigned short* Pf = (w == 0) ? Ptq : (w == 1) ? Ptk : Ptv;
      const char* xs = smem + w * 6144;
      f32x4 acc[2][2] = {{zf, zf}, {zf, zf}};
#pragma unroll
      for (int ks = 0; ks < 4; ++ks) {
        bf16x8 Bf[2], Af[2];
#pragma unroll
        for (int ntl = 0; ntl < 2; ++ntl)
          Bf[ntl] = *(const bf16x8*)(Pf + (size_t)(((n * 8 + (wv * 2 + ntl)) * 4 + ks) * 64 + lane) * 8);
#pragma unroll
        for (int mt = 0; mt < 2; ++mt) {
          int row = mt * 16 + c; row = row < 24 ? row : 23;
          Af[mt] = *(const bf16x8*)(xs + swz256((unsigned)(row * 256 + ks * 64 + g * 16)));
        }
        __builtin_amdgcn_s_setprio(1);
#pragma unroll
        for (int mt = 0; mt < 2; ++mt)
#pragma unroll
          for (int ntl = 0; ntl < 2; ++ntl)
            acc[mt][ntl] = __builtin_amdgcn_mfma_f32_16x16x32_bf16(Af[mt], Bf[ntl], acc[mt][ntl], 0, 0, 0);
        __builtin_amdgcn_s_setprio(0);
      }
      const float ps = (w == 0) ? 0.25f : 1.0f;   // fold softmax scale into q
      P8 r;
#pragma unroll
      for (int mt = 0; mt < 2; ++mt)
#pragma unroll
        for (int ntl = 0; ntl < 2; ++ntl)
#pragma unroll
          for (int half = 0; half < 2; ++half) {
            float a = fmaxf(acc[mt][ntl][half * 2], 0.f) * ps;
            float bb = fmaxf(acc[mt][ntl][half * 2 + 1], 0.f) * ps;
            r.u[(mt * 2 + ntl) * 2 + half] = cvtpk(a, bb);
          }
      if (w == 0) pq = r; else if (w == 1) pk_ = r; else pv_ = r;
    }
  }
  __syncthreads();  // (2) all staging reads done -> arenas live

  char* arena = smem + wv * 4608;

  // ---- P2a: unpack packed projections into arena slices ----
#pragma unroll
  for (int mt = 0; mt < 2; ++mt)
#pragma unroll
    for (int ntl = 0; ntl < 2; ++ntl)
#pragma unroll
      for (int half = 0; half < 2; ++half) {
        unsigned uq = pq.u[(mt * 2 + ntl) * 2 + half];
        unsigned uk = pk_.u[(mt * 2 + ntl) * 2 + half];
        unsigned uv = pv_.u[(mt * 2 + ntl) * 2 + half];
        int row0 = mt * 16 + g * 4 + half * 2;
        // vT: rows adjacent in [e][t] layout -> single uint store (both rows)
        if (row0 < 24)
          *(unsigned*)(arena + 3072 + (ntl * 16 + c) * 48 + row0 * 2) = uv;
#pragma unroll
        for (int rr = 0; rr < 2; ++rr) {
          int row = row0 + rr;
          if (row < 24) {
            unsigned short vq = (unsigned short)(rr ? (uq >> 16) : uq);
            unsigned short vk = (unsigned short)(rr ? (uk >> 16) : uk);
            unsigned adqk = (unsigned)(row * 64) +
                            (((unsigned)(ntl * 32 + c * 2)) ^ (((unsigned)row & 3u) << 4));
            *(unsigned short*)(arena + adqk) = vq;
            *(unsigned short*)(arena + 1536 + adqk) = vk;
          }
        }
      }

  // ---- P2b: score fragments (all reads BEFORE probs overlay writes) ----
  bf16x8 Aq[2][2], Bk[2][2];   // [hh][mt/st]; k-dim = 16, g>=2 zero
#pragma unroll
  for (int hh = 0; hh < 2; ++hh)
#pragma unroll
    for (int mt = 0; mt < 2; ++mt) {
      int row = mt * 16 + c; row = row < 24 ? row : 23;
      unsigned ad = (unsigned)(row * 64) +
                    (((unsigned)(hh * 32 + g * 16)) ^ (((unsigned)row & 3u) << 4));
      Aq[hh][mt] = zb;
      Bk[hh][mt] = zb;
      if (g < 2) {
        Aq[hh][mt] = *(const bf16x8*)(arena + ad);
        Bk[hh][mt] = *(const bf16x8*)(arena + 1536 + ad);
      }
    }

  // ---- P2c: scores + exp; store UNNORMALIZED probs (no shuffles, no reduce) ----
#pragma unroll
  for (int hh = 0; hh < 2; ++hh) {
    f32x4 sc[2][2];
    __builtin_amdgcn_s_setprio(1);
#pragma unroll
    for (int mt = 0; mt < 2; ++mt)
#pragma unroll
      for (int st = 0; st < 2; ++st)
        sc[mt][st] = __builtin_amdgcn_mfma_f32_16x16x32_bf16(Aq[hh][mt], Bk[hh][st], zf, 0, 0, 0);
    __builtin_amdgcn_s_setprio(0);
#pragma unroll
    for (int mt = 0; mt < 2; ++mt)
#pragma unroll
      for (int r = 0; r < 4; ++r) {
        int t = mt * 16 + g * 4 + r;
        float e0 = (c <= t)      ? __expf(sc[mt][0][r]) : 0.f;   // bounded by e^9
        float e1 = (16 + c <= t) ? __expf(sc[mt][1][r]) : 0.f;
        if (t < 24) {
          unsigned u = cvtpk(e0, e1);
          *(unsigned short*)(arena + hh * 1152 + t * 48 + c * 2) = (unsigned short)u;
          if (c < 8)
            *(unsigned short*)(arena + hh * 1152 + t * 48 + (16 + c) * 2) = (unsigned short)(u >> 16);
        }
      }
  }

  // ---- P2d: row-sum MFMA (B=ones) + PV; normalize in regs; attn; outh ----
  {
    bf16x8 Ap[2][2], Bv[2];
    const short one_bf = (short)0x3F80;
    bf16x8 onesf = {one_bf, one_bf, one_bf, one_bf, one_bf, one_bf, one_bf, one_bf};
    if (g >= 3) onesf = zb;   // k = g*8+j < 24 only
#pragma unroll
    for (int hh = 0; hh < 2; ++hh) {
      Bv[hh] = zb;
      if (g < 3) Bv[hh] = *(const bf16x8*)(arena + 3072 + (hh * 16 + c) * 48 + g * 16);
#pragma unroll
      for (int mt = 0; mt < 2; ++mt) {
        int row = mt * 16 + c; row = row < 24 ? row : 23;
        Ap[hh][mt] = zb;
        if (g < 3) Ap[hh][mt] = *(const bf16x8*)(arena + hh * 1152 + row * 48 + g * 16);
      }
    }
    f32x4 pv[2][2], su[2][2];
    __builtin_amdgcn_s_setprio(1);
#pragma unroll
    for (int hh = 0; hh < 2; ++hh)
#pragma unroll
      for (int mt = 0; mt < 2; ++mt) {
        su[hh][mt] = __builtin_amdgcn_mfma_f32_16x16x32_bf16(Ap[hh][mt], onesf, zf, 0, 0, 0);
        pv[hh][mt] = __builtin_amdgcn_mfma_f32_16x16x32_bf16(Ap[hh][mt], Bv[hh], zf, 0, 0, 0);
      }
    __builtin_amdgcn_s_setprio(0);
    // normalize pv rows; store inv (rows t = mt*16+g*4+r) for the attn write
#pragma unroll
    for (int hh = 0; hh < 2; ++hh)
#pragma unroll
      for (int mt = 0; mt < 2; ++mt) {
        float iv[4];
#pragma unroll
        for (int r = 0; r < 4; ++r) {
          iv[r] = __builtin_amdgcn_rcpf(su[hh][mt][r]);   // sum >= 1 for valid t
          pv[hh][mt][r] *= iv[r];
        }
        if (c == 0) {
#pragma unroll
          for (int rp = 0; rp < 4; rp += 2) {
            int t0 = mt * 16 + g * 4 + rp;
            if (t0 < 24) {
              float2 st2 = {iv[rp], iv[rp + 1]};
              *(float2*)(arena + 2304 + hh * 96 + t0 * 4) = st2;
            }
          }
        }
      }
    // attn global write: p_un * inv[t] (coalesced float4)
    const size_t abase = (size_t)(b * Nn + n) * (Hh * Tt * Tt);
#pragma unroll
    for (int i = 0; i < 5; ++i) {
      int idx = lane + 64 * i;
      if (idx < 288) {
        int hh = idx / 144;
        int rem = idx - hh * 144;
        int t = rem / 6;
        int s4g = rem - t * 6;
        uint2 pr = *(const uint2*)(arena + hh * 1152 + t * 48 + s4g * 8);
        float iv0 = *(const float*)(arena + 2304 + hh * 96 + t * 4);
        float4 o;
        o.x = __uint_as_float((pr.x & 0xFFFFu) << 16) * iv0;
        o.y = __uint_as_float(pr.x & 0xFFFF0000u) * iv0;
        o.z = __uint_as_float((pr.y & 0xFFFFu) << 16) * iv0;
        o.w = __uint_as_float(pr.y & 0xFFFF0000u) * iv0;
        *(float4*)(attn + abase + (size_t)(wv * 2 + hh) * 576 + t * 24 + s4g * 4) = o;
      }
    }
    // outh
#pragma unroll
    for (int hh = 0; hh < 2; ++hh) {
      int h = wv * 2 + hh;
#pragma unroll
      for (int mt = 0; mt < 2; ++mt)
#pragma unroll
        for (int r = 0; r < 4; ++r) {
          int t = mt * 16 + g * 4 + r;
          if (t < 24)
            *(unsigned short*)(smem + 18432 + swz256((unsigned)(t * 256 + (h * 16 + c) * 2))) =
                f2bs(pv[hh][mt][r]);
        }
    }
  }

  // prefetch W B-frags (hide L2 latency under barrier)
  bf16x8 Bw[4];
#pragma unroll
  for (int ks = 0; ks < 4; ++ks)
    Bw[ks] = *(const bf16x8*)(Wt + (size_t)((wv * 4 + ks) * 64 + lane) * 8);
  __syncthreads();  // (3) outh complete

  // ---- P3: out projection ----
  {
    f32x4 acc2[2] = {zf, zf};
#pragma unroll
    for (int ks = 0; ks < 4; ++ks) {
      bf16x8 Af[2];
#pragma unroll
      for (int mt = 0; mt < 2; ++mt) {
        int row = mt * 16 + c; row = row < 24 ? row : 23;
        Af[mt] = *(const bf16x8*)(smem + 18432 + swz256((unsigned)(row * 256 + ks * 64 + g * 16)));
      }
      __builtin_amdgcn_s_setprio(1);
#pragma unroll
      for (int mt = 0; mt < 2; ++mt)
        acc2[mt] = __builtin_amdgcn_mfma_f32_16x16x32_bf16(Af[mt], Bw[ks], acc2[mt], 0, 0, 0);
      __builtin_amdgcn_s_setprio(0);
    }
    int j = wv * 16 + c;
    float bj = bias[j];
    const size_t obase = (size_t)(b * Nn + n) * (Tt * Dm);
#pragma unroll
    for (int mt = 0; mt < 2; ++mt)
#pragma unroll
      for (int r = 0; r < 4; ++r) {
        int t = mt * 16 + g * 4 + r;
        if (t < 24) out[obase + (size_t)t * Dm + j] = fmaxf(acc2[mt][r] + bj, 0.f);
      }
  }
}

extern "C" void kernel_launch(void* const* d_in, const int* in_sizes, int n_in,
                              void* d_out, int out_size, void* d_ws, size_t ws_size,
                              hipStream_t stream) {
  const float* query = (const float*)d_in[0];
  const float* key   = (const float*)d_in[1];
  const float* value = (const float*)d_in[2];
  const float* qp1 = (const float*)d_in[4];
  const float* qp2 = (const float*)d_in[5];
  const float* kp1 = (const float*)d_in[6];
  const float* kp2 = (const float*)d_in[7];
  const float* vp1 = (const float*)d_in[8];
  const float* vp2 = (const float*)d_in[9];
  const float* out_W = (const float*)d_in[10];
  const float* out_b = (const float*)d_in[11];

  unsigned short* Pt  = (unsigned short*)d_ws;        // 3*PT bf16
  unsigned short* Wtf = Pt + 3 * PT;                  // 8192 bf16

  float* out = (float*)d_out;
  float* attn = out + (size_t)NBN * Tt * Dm;

  build_P_frag3<<<dim3(Nn * 8, 3), 256, 0, stream>>>(qp1, qp2, kp1, kp2, vp1, vp2, Pt);
  build_W_frag<<<1, 256, 0, stream>>>(out_W, Wtf);
  fused_attn<<<NBN, 256, 0, stream>>>(query, key, value,
                                      Pt, Pt + PT, Pt + 2 * PT, Wtf,
                                      out_b, out, attn);
}